// Round 7
// baseline (127.731 us; speedup 1.0000x reference)
//
#include <hip/hip_runtime.h>
#include <math.h>

// RandomMicEQ: cascade of 3 biquads (EQ -> LP -> HP), stage outputs clamped
// to [-1,1], recursion history UNCLAMPED (matches jax ref).
//
// R10: single-variable change vs R9: __launch_bounds__(64,2) -> (64,4).
// History: R8 = (64,4) + lambdas -> SROA failure -> d[64] in scratch
// (VGPR_Count=64, ~32cyc/instr). R9 = straight-line + (64,2) -> no spill
// but allocator free to exceed 128 VGPR -> only 2 waves/SIMD resident
// (gfx950 occupancy steps at 64/128/256) vs 3.53 waves/SIMD of work ->
// two serial rounds, latency re-exposed; kernel ~34us (bench-additive
// model), no better than R7/R8. R10 = straight-line + 128-VGPR cap:
// demand ~100 (d[64] + ~35 overhead) fits -> no spill AND 4 waves/SIMD.
// Diagnostic: VGPR_Count must read ~96-128; if 64, spill returned.
//
// Algorithm (R6-R9): per stage, lanes run a zero-state local pass in
// registers; 6-step Kogge-Stone scan of 2-dim states (A^64 powers, host
// double) reconstructs exact init states; correction = homogeneous
// recursion seeded by init state; clamp at consumption; stage-k correction
// fused into stage-(k+1) local sweep (4 sweeps total). Block boundary =
// zero state 192 samples early (3 warm chunks discarded). Block 0 exact.
// Input: direct strided global->register (disjoint chunks, ~1.05x fetch).
// Output: LDS transpose (pitch 65, conflict-free) + full-line coalesced
// stores (R2: scattered stores cause RMW write amplification).

struct BQ { float b0, b1, b2, a1, a2; };
struct ScanM { float m[6][4]; };       // A64^(2^k), k=0..5, row-major 2x2

#define L_CHUNK 64
#define NWARM   3
#define NCH     64                     // chunks per block (= lanes)
#define NOUT    (NCH - NWARM)          // 61
#define SPAN    (NCH * L_CHUNK)        // 4096
#define HALF    (SPAN / 2)             // 2048
#define OUTSPAN (NOUT * L_CHUNK)       // 3904
#define WOFF    (NWARM * L_CHUNK)      // 192
#define BUF_P   (HALF + HALF / 64)     // 2080 dwords = 8320 B

__device__ __forceinline__ float clamp1(float v) {
    return fminf(fmaxf(v, -1.f), 1.f);
}

// Kogge-Stone inclusive scan of s_i = A64 * s_{i-1} + loc_i over 64 lanes
#define KS_SCAN(S)                                                   \
    _Pragma("unroll")                                                \
    for (int k = 0; k < 6; ++k) {                                    \
        float px = __shfl_up(sx, 1 << k, 64);                        \
        float py = __shfl_up(sy, 1 << k, 64);                        \
        if (lane >= (1 << k)) {                                      \
            sx += S.m[k][0]*px + S.m[k][1]*py;                       \
            sy += S.m[k][2]*px + S.m[k][3]*py;                       \
        }                                                            \
    }

__global__ __launch_bounds__(64, 4) void biquad3_kernel(
    const float* __restrict__ x, float* __restrict__ out, int T,
    BQ F1, BQ F2, BQ F3, ScanM S1, ScanM S2, ScanM S3)
{
    __shared__ float buf[BUF_P];             // output transpose staging only

    const int lane = threadIdx.x;
    const int row  = blockIdx.y;
    const int col0 = blockIdx.x * OUTSPAN;
    const int base = col0 - WOFF;            // may be < 0 (zero-padded)

    const float* xr = x   + (size_t)row * T;
    float*       yr = out + (size_t)row * T;

    float d[64];                             // lane's chunk: MUST be VGPRs

    // ---- direct strided load of lane's 64-sample chunk ----
    const int cbase = base + lane * L_CHUNK;
    if (cbase >= 0 && cbase + L_CHUNK <= T) {
#pragma unroll
        for (int j = 0; j < 16; ++j) {
            float4 v = *(const float4*)(xr + cbase + 4*j);
            d[4*j+0] = v.x; d[4*j+1] = v.y; d[4*j+2] = v.z; d[4*j+3] = v.w;
        }
    } else {                                 // boundary lanes only
#pragma unroll
        for (int j = 0; j < 64; ++j) {
            int g = cbase + j;
            d[j] = ((unsigned)g < (unsigned)T) ? xr[g] : 0.f;
        }
    }

    // ================= pass 1: stage-1 local filter =================
    float ph1 = __shfl_up(d[63], 1, 64);     // raw-input prehistory
    float ph2 = __shfl_up(d[62], 1, 64);
    if (lane == 0) { ph1 = 0.f; ph2 = 0.f; }
    float xx1 = ph1, xx2 = ph2, yy1 = 0.f, yy2 = 0.f;
#pragma unroll
    for (int t = 0; t < 64; ++t) {
        float v = d[t];
        float f = F1.b0*v + F1.b1*xx1 + F1.b2*xx2;
        float y = (f - F1.a2*yy2) - F1.a1*yy1;
        xx2 = xx1; xx1 = v; yy2 = yy1; yy1 = y;
        d[t] = y;                            // unclamped stage-1 local
    }
    float sx = yy1, sy = yy2;
    KS_SCAN(S1)
    float ix = __shfl_up(sx, 1, 64);         // exclusive: my init (y-1,y-2)
    float iy = __shfl_up(sy, 1, 64);
    if (lane == 0) { ix = 0.f; iy = 0.f; }
    // corrected stage-1 tail (closed form) -> next stage's prehistory
    float ct1 = clamp1(d[63] + S1.m[0][0]*ix + S1.m[0][1]*iy);
    float ct2 = clamp1(d[62] + S1.m[0][2]*ix + S1.m[0][3]*iy);
    ph1 = __shfl_up(ct1, 1, 64);
    ph2 = __shfl_up(ct2, 1, 64);
    if (lane == 0) { ph1 = 0.f; ph2 = 0.f; }

    // ===== pass 2 fused: stage-1 correction+clamp + stage-2 local =====
    float h1 = ix, h2 = iy;
    xx1 = ph1; xx2 = ph2; yy1 = 0.f; yy2 = 0.f;
#pragma unroll
    for (int t = 0; t < 64; ++t) {
        float h = -F1.a1*h1 - F1.a2*h2;      // stage-1 homogeneous corr
        float v = clamp1(d[t] + h);          // exact stage-1 output
        h2 = h1; h1 = h;
        float f = F2.b0*v + F2.b1*xx1 + F2.b2*xx2;
        float y = (f - F2.a2*yy2) - F2.a1*yy1;
        xx2 = xx1; xx1 = v; yy2 = yy1; yy1 = y;
        d[t] = y;                            // unclamped stage-2 local
    }
    sx = yy1; sy = yy2;
    KS_SCAN(S2)
    ix = __shfl_up(sx, 1, 64);
    iy = __shfl_up(sy, 1, 64);
    if (lane == 0) { ix = 0.f; iy = 0.f; }
    ct1 = clamp1(d[63] + S2.m[0][0]*ix + S2.m[0][1]*iy);
    ct2 = clamp1(d[62] + S2.m[0][2]*ix + S2.m[0][3]*iy);
    ph1 = __shfl_up(ct1, 1, 64);
    ph2 = __shfl_up(ct2, 1, 64);
    if (lane == 0) { ph1 = 0.f; ph2 = 0.f; }

    // ===== pass 3 fused: stage-2 correction+clamp + stage-3 local =====
    h1 = ix; h2 = iy;
    xx1 = ph1; xx2 = ph2; yy1 = 0.f; yy2 = 0.f;
#pragma unroll
    for (int t = 0; t < 64; ++t) {
        float h = -F2.a1*h1 - F2.a2*h2;
        float v = clamp1(d[t] + h);
        h2 = h1; h1 = h;
        float f = F3.b0*v + F3.b1*xx1 + F3.b2*xx2;
        float y = (f - F3.a2*yy2) - F3.a1*yy1;
        xx2 = xx1; xx1 = v; yy2 = yy1; yy1 = y;
        d[t] = y;                            // unclamped stage-3 local
    }
    sx = yy1; sy = yy2;
    KS_SCAN(S3)
    ix = __shfl_up(sx, 1, 64);
    iy = __shfl_up(sy, 1, 64);
    if (lane == 0) { ix = 0.f; iy = 0.f; }

    // ===== stage-3 correction + clamp =====
    h1 = ix; h2 = iy;
#pragma unroll
    for (int t = 0; t < 64; ++t) {
        float h = -F3.a1*h1 - F3.a2*h2;
        d[t] = clamp1(d[t] + h);
        h2 = h1; h1 = h;
    }

    // ---- output transpose + coalesced flush, two halves ----
    if (lane < 32) {
        const int b0i = lane * 65;           // stride 65: conflict-free
#pragma unroll
        for (int t = 0; t < 64; ++t) buf[b0i + t] = d[t];
    }
    __syncthreads();
    for (int mm = WOFF + lane * 4; mm < HALF; mm += 256) {
        int pm = mm + (mm >> 6);
        int g  = col0 + mm - WOFF;           // g%4==0, T%4==0
        if (g < T) {
            float4 v4 = make_float4(buf[pm+0], buf[pm+1], buf[pm+2], buf[pm+3]);
            *(float4*)(yr + g) = v4;
        }
    }
    __syncthreads();                         // WAR before half B writes
    if (lane >= 32) {
        const int b0i = (lane - 32) * 65;
#pragma unroll
        for (int t = 0; t < 64; ++t) buf[b0i + t] = d[t];
    }
    __syncthreads();
    for (int mm = HALF + lane * 4; mm < SPAN; mm += 256) {
        int mo = mm - HALF;
        int pm = mo + (mo >> 6);
        int g  = col0 + mm - WOFF;
        if (g < T) {
            float4 v4 = make_float4(buf[pm+0], buf[pm+1], buf[pm+2], buf[pm+3]);
            *(float4*)(yr + g) = v4;
        }
    }
}

// ---- host side ----------------------------------------------------------

static void norm_ba(double b0, double b1, double b2,
                    double a0, double a1, double a2, BQ* r,
                    double* oa1, double* oa2) {
    r->b0 = (float)(b0/a0); r->b1 = (float)(b1/a0); r->b2 = (float)(b2/a0);
    r->a1 = (float)(a1/a0); r->a2 = (float)(a2/a0);
    // scan matrices built from the float-rounded coeffs the kernel iterates
    *oa1 = (double)r->a1; *oa2 = (double)r->a2;
}

static void make_eq(double f0, double gain_db, double Q, BQ* r, double* a1, double* a2) {
    const double SR = 44100.0;
    double w0 = 2.0 * M_PI * f0 / SR;
    double alpha = sin(w0) / (2.0 * Q);
    double A = pow(10.0, gain_db / 40.0);
    norm_ba(1.0 + alpha*A, -2.0*cos(w0), 1.0 - alpha*A,
            1.0 + alpha/A, -2.0*cos(w0), 1.0 - alpha/A, r, a1, a2);
}

static void make_lp(double cutoff, double Q, BQ* r, double* a1, double* a2) {
    const double SR = 44100.0;
    double w0 = 2.0 * M_PI * cutoff / SR;
    double alpha = sin(w0) / (2.0 * Q);
    double c = cos(w0);
    norm_ba((1.0-c)/2.0, 1.0-c, (1.0-c)/2.0,
            1.0+alpha, -2.0*c, 1.0-alpha, r, a1, a2);
}

static void make_hp(double cutoff, double Q, BQ* r, double* a1, double* a2) {
    const double SR = 44100.0;
    double w0 = 2.0 * M_PI * cutoff / SR;
    double alpha = sin(w0) / (2.0 * Q);
    double c = cos(w0);
    norm_ba((1.0+c)/2.0, -(1.0+c), (1.0+c)/2.0,
            1.0+alpha, -2.0*c, 1.0-alpha, r, a1, a2);
}

// S.m[k] = A64^(2^k) where A = [[-a1,-a2],[1,0]], all double math
static void fill_scan(double a1, double a2, ScanM* S) {
    double M[4] = { -a1, -a2, 1.0, 0.0 };    // A^1
    for (int i = 0; i < 6; ++i) {            // -> A^64
        double n0 = M[0]*M[0] + M[1]*M[2], n1 = M[0]*M[1] + M[1]*M[3];
        double n2 = M[2]*M[0] + M[3]*M[2], n3 = M[2]*M[1] + M[3]*M[3];
        M[0]=n0; M[1]=n1; M[2]=n2; M[3]=n3;
    }
    for (int k = 0; k < 6; ++k) {            // A64^(2^k)
        S->m[k][0] = (float)M[0]; S->m[k][1] = (float)M[1];
        S->m[k][2] = (float)M[2]; S->m[k][3] = (float)M[3];
        double n0 = M[0]*M[0] + M[1]*M[2], n1 = M[0]*M[1] + M[1]*M[3];
        double n2 = M[2]*M[0] + M[3]*M[2], n3 = M[2]*M[1] + M[3]*M[3];
        M[0]=n0; M[1]=n1; M[2]=n2; M[3]=n3;
    }
}

extern "C" void kernel_launch(void* const* d_in, const int* in_sizes, int n_in,
                              void* d_out, int out_size, void* d_ws, size_t ws_size,
                              hipStream_t stream) {
    const float* x = (const float*)d_in[0];
    float* out = (float*)d_out;

    const int T = 441000;
    int total = in_sizes[0];
    int B = total / T;                                  // 32

    BQ f1, f2, f3; double a1, a2;
    ScanM s1, s2, s3;
    make_eq(1000.0, 6.0, 1.0, &f1, &a1, &a2);           fill_scan(a1, a2, &s1);
    make_lp(8000.0, 0.7071067811865476, &f2, &a1, &a2); fill_scan(a1, a2, &s2);
    make_hp(300.0, 0.7071067811865476, &f3, &a1, &a2);  fill_scan(a1, a2, &s3);

    int blocksPerRow = (T + OUTSPAN - 1) / OUTSPAN;     // 113
    dim3 grid(blocksPerRow, B);
    hipLaunchKernelGGL(biquad3_kernel, grid, dim3(64), 0, stream,
                       x, out, T, f1, f2, f3, s1, s2, s3);
}

// Round 8
// 126.645 us; speedup vs baseline: 1.0086x; 1.0086x over previous
//
#include <hip/hip_runtime.h>
#include <math.h>

// RandomMicEQ: cascade of 3 biquads (EQ -> LP -> HP), stage outputs clamped
// to [-1,1], recursion history UNCLAMPED (matches jax ref).
//
// R11: pin occupancy with amdgpu_waves_per_eu(4,4). Single-variable change
// vs R10. Evidence chain:
//   R8  (64,4)+lambdas:       VGPR=64, spill, 47.6us
//   R9  (64,2)+straight-line: no spill but >128 VGPR -> 2 waves/SIMD, ~34us
//   R10 (64,4)+straight-line: VGPR=64 AGAIN -> wholesale d[] demotion;
//        scratch leaked past L2 (WRITE 55->79MB, FETCH 30->39MB), 65.9us.
// Conclusion: __launch_bounds__ 2nd arg is only a MIN; the backend's
// occupancy heuristic targets 8 waves/SIMD (64-VGPR budget) for 64-thread
// blocks and spills d[64] to get there. amdgpu_waves_per_eu(4,4) pins
// min=max=4: budget 128 VGPR (demand ~100 fits, no spill) AND full
// residency (4 waves/SIMD x 4 SIMD = 16 waves/CU >= 14.1 waves/CU of work).
// Diagnostic: VGPR_Count ~96-128 = success; 64 = attribute ignored.
//
// Algorithm (R6-R9): per stage, lanes run a zero-state local pass in
// registers; 6-step Kogge-Stone scan of 2-dim states (A^64 powers, host
// double) reconstructs exact init states; correction = homogeneous
// recursion seeded by init state; clamp at consumption; stage-k correction
// fused into stage-(k+1) local sweep (4 sweeps total). Block boundary =
// zero state 192 samples early (3 warm chunks discarded). Block 0 exact.
// Input: direct strided global->register (disjoint chunks, ~1.05x fetch).
// Output: LDS transpose (pitch 65, conflict-free) + full-line coalesced
// stores (R2: scattered stores cause RMW write amplification).

struct BQ { float b0, b1, b2, a1, a2; };
struct ScanM { float m[6][4]; };       // A64^(2^k), k=0..5, row-major 2x2

#define L_CHUNK 64
#define NWARM   3
#define NCH     64                     // chunks per block (= lanes)
#define NOUT    (NCH - NWARM)          // 61
#define SPAN    (NCH * L_CHUNK)        // 4096
#define HALF    (SPAN / 2)             // 2048
#define OUTSPAN (NOUT * L_CHUNK)       // 3904
#define WOFF    (NWARM * L_CHUNK)      // 192
#define BUF_P   (HALF + HALF / 64)     // 2080 dwords = 8320 B

__device__ __forceinline__ float clamp1(float v) {
    return fminf(fmaxf(v, -1.f), 1.f);
}

// Kogge-Stone inclusive scan of s_i = A64 * s_{i-1} + loc_i over 64 lanes
#define KS_SCAN(S)                                                   \
    _Pragma("unroll")                                                \
    for (int k = 0; k < 6; ++k) {                                    \
        float px = __shfl_up(sx, 1 << k, 64);                        \
        float py = __shfl_up(sy, 1 << k, 64);                        \
        if (lane >= (1 << k)) {                                      \
            sx += S.m[k][0]*px + S.m[k][1]*py;                       \
            sy += S.m[k][2]*px + S.m[k][3]*py;                       \
        }                                                            \
    }

__global__ __launch_bounds__(64)
__attribute__((amdgpu_waves_per_eu(4, 4)))
void biquad3_kernel(
    const float* __restrict__ x, float* __restrict__ out, int T,
    BQ F1, BQ F2, BQ F3, ScanM S1, ScanM S2, ScanM S3)
{
    __shared__ float buf[BUF_P];             // output transpose staging only

    const int lane = threadIdx.x;
    const int row  = blockIdx.y;
    const int col0 = blockIdx.x * OUTSPAN;
    const int base = col0 - WOFF;            // may be < 0 (zero-padded)

    const float* xr = x   + (size_t)row * T;
    float*       yr = out + (size_t)row * T;

    float d[64];                             // lane's chunk: MUST be VGPRs

    // ---- direct strided load of lane's 64-sample chunk ----
    const int cbase = base + lane * L_CHUNK;
    if (cbase >= 0 && cbase + L_CHUNK <= T) {
#pragma unroll
        for (int j = 0; j < 16; ++j) {
            float4 v = *(const float4*)(xr + cbase + 4*j);
            d[4*j+0] = v.x; d[4*j+1] = v.y; d[4*j+2] = v.z; d[4*j+3] = v.w;
        }
    } else {                                 // boundary lanes only
#pragma unroll
        for (int j = 0; j < 64; ++j) {
            int g = cbase + j;
            d[j] = ((unsigned)g < (unsigned)T) ? xr[g] : 0.f;
        }
    }

    // ================= pass 1: stage-1 local filter =================
    float ph1 = __shfl_up(d[63], 1, 64);     // raw-input prehistory
    float ph2 = __shfl_up(d[62], 1, 64);
    if (lane == 0) { ph1 = 0.f; ph2 = 0.f; }
    float xx1 = ph1, xx2 = ph2, yy1 = 0.f, yy2 = 0.f;
#pragma unroll
    for (int t = 0; t < 64; ++t) {
        float v = d[t];
        float f = F1.b0*v + F1.b1*xx1 + F1.b2*xx2;
        float y = (f - F1.a2*yy2) - F1.a1*yy1;
        xx2 = xx1; xx1 = v; yy2 = yy1; yy1 = y;
        d[t] = y;                            // unclamped stage-1 local
    }
    float sx = yy1, sy = yy2;
    KS_SCAN(S1)
    float ix = __shfl_up(sx, 1, 64);         // exclusive: my init (y-1,y-2)
    float iy = __shfl_up(sy, 1, 64);
    if (lane == 0) { ix = 0.f; iy = 0.f; }
    // corrected stage-1 tail (closed form) -> next stage's prehistory
    float ct1 = clamp1(d[63] + S1.m[0][0]*ix + S1.m[0][1]*iy);
    float ct2 = clamp1(d[62] + S1.m[0][2]*ix + S1.m[0][3]*iy);
    ph1 = __shfl_up(ct1, 1, 64);
    ph2 = __shfl_up(ct2, 1, 64);
    if (lane == 0) { ph1 = 0.f; ph2 = 0.f; }

    // ===== pass 2 fused: stage-1 correction+clamp + stage-2 local =====
    float h1 = ix, h2 = iy;
    xx1 = ph1; xx2 = ph2; yy1 = 0.f; yy2 = 0.f;
#pragma unroll
    for (int t = 0; t < 64; ++t) {
        float h = -F1.a1*h1 - F1.a2*h2;      // stage-1 homogeneous corr
        float v = clamp1(d[t] + h);          // exact stage-1 output
        h2 = h1; h1 = h;
        float f = F2.b0*v + F2.b1*xx1 + F2.b2*xx2;
        float y = (f - F2.a2*yy2) - F2.a1*yy1;
        xx2 = xx1; xx1 = v; yy2 = yy1; yy1 = y;
        d[t] = y;                            // unclamped stage-2 local
    }
    sx = yy1; sy = yy2;
    KS_SCAN(S2)
    ix = __shfl_up(sx, 1, 64);
    iy = __shfl_up(sy, 1, 64);
    if (lane == 0) { ix = 0.f; iy = 0.f; }
    ct1 = clamp1(d[63] + S2.m[0][0]*ix + S2.m[0][1]*iy);
    ct2 = clamp1(d[62] + S2.m[0][2]*ix + S2.m[0][3]*iy);
    ph1 = __shfl_up(ct1, 1, 64);
    ph2 = __shfl_up(ct2, 1, 64);
    if (lane == 0) { ph1 = 0.f; ph2 = 0.f; }

    // ===== pass 3 fused: stage-2 correction+clamp + stage-3 local =====
    h1 = ix; h2 = iy;
    xx1 = ph1; xx2 = ph2; yy1 = 0.f; yy2 = 0.f;
#pragma unroll
    for (int t = 0; t < 64; ++t) {
        float h = -F2.a1*h1 - F2.a2*h2;
        float v = clamp1(d[t] + h);
        h2 = h1; h1 = h;
        float f = F3.b0*v + F3.b1*xx1 + F3.b2*xx2;
        float y = (f - F3.a2*yy2) - F3.a1*yy1;
        xx2 = xx1; xx1 = v; yy2 = yy1; yy1 = y;
        d[t] = y;                            // unclamped stage-3 local
    }
    sx = yy1; sy = yy2;
    KS_SCAN(S3)
    ix = __shfl_up(sx, 1, 64);
    iy = __shfl_up(sy, 1, 64);
    if (lane == 0) { ix = 0.f; iy = 0.f; }

    // ===== stage-3 correction + clamp =====
    h1 = ix; h2 = iy;
#pragma unroll
    for (int t = 0; t < 64; ++t) {
        float h = -F3.a1*h1 - F3.a2*h2;
        d[t] = clamp1(d[t] + h);
        h2 = h1; h1 = h;
    }

    // ---- output transpose + coalesced flush, two halves ----
    if (lane < 32) {
        const int b0i = lane * 65;           // stride 65: conflict-free
#pragma unroll
        for (int t = 0; t < 64; ++t) buf[b0i + t] = d[t];
    }
    __syncthreads();
    for (int mm = WOFF + lane * 4; mm < HALF; mm += 256) {
        int pm = mm + (mm >> 6);
        int g  = col0 + mm - WOFF;           // g%4==0, T%4==0
        if (g < T) {
            float4 v4 = make_float4(buf[pm+0], buf[pm+1], buf[pm+2], buf[pm+3]);
            *(float4*)(yr + g) = v4;
        }
    }
    __syncthreads();                         // WAR before half B writes
    if (lane >= 32) {
        const int b0i = (lane - 32) * 65;
#pragma unroll
        for (int t = 0; t < 64; ++t) buf[b0i + t] = d[t];
    }
    __syncthreads();
    for (int mm = HALF + lane * 4; mm < SPAN; mm += 256) {
        int mo = mm - HALF;
        int pm = mo + (mo >> 6);
        int g  = col0 + mm - WOFF;
        if (g < T) {
            float4 v4 = make_float4(buf[pm+0], buf[pm+1], buf[pm+2], buf[pm+3]);
            *(float4*)(yr + g) = v4;
        }
    }
}

// ---- host side ----------------------------------------------------------

static void norm_ba(double b0, double b1, double b2,
                    double a0, double a1, double a2, BQ* r,
                    double* oa1, double* oa2) {
    r->b0 = (float)(b0/a0); r->b1 = (float)(b1/a0); r->b2 = (float)(b2/a0);
    r->a1 = (float)(a1/a0); r->a2 = (float)(a2/a0);
    // scan matrices built from the float-rounded coeffs the kernel iterates
    *oa1 = (double)r->a1; *oa2 = (double)r->a2;
}

static void make_eq(double f0, double gain_db, double Q, BQ* r, double* a1, double* a2) {
    const double SR = 44100.0;
    double w0 = 2.0 * M_PI * f0 / SR;
    double alpha = sin(w0) / (2.0 * Q);
    double A = pow(10.0, gain_db / 40.0);
    norm_ba(1.0 + alpha*A, -2.0*cos(w0), 1.0 - alpha*A,
            1.0 + alpha/A, -2.0*cos(w0), 1.0 - alpha/A, r, a1, a2);
}

static void make_lp(double cutoff, double Q, BQ* r, double* a1, double* a2) {
    const double SR = 44100.0;
    double w0 = 2.0 * M_PI * cutoff / SR;
    double alpha = sin(w0) / (2.0 * Q);
    double c = cos(w0);
    norm_ba((1.0-c)/2.0, 1.0-c, (1.0-c)/2.0,
            1.0+alpha, -2.0*c, 1.0-alpha, r, a1, a2);
}

static void make_hp(double cutoff, double Q, BQ* r, double* a1, double* a2) {
    const double SR = 44100.0;
    double w0 = 2.0 * M_PI * cutoff / SR;
    double alpha = sin(w0) / (2.0 * Q);
    double c = cos(w0);
    norm_ba((1.0+c)/2.0, -(1.0+c), (1.0+c)/2.0,
            1.0+alpha, -2.0*c, 1.0-alpha, r, a1, a2);
}

// S.m[k] = A64^(2^k) where A = [[-a1,-a2],[1,0]], all double math
static void fill_scan(double a1, double a2, ScanM* S) {
    double M[4] = { -a1, -a2, 1.0, 0.0 };    // A^1
    for (int i = 0; i < 6; ++i) {            // -> A^64
        double n0 = M[0]*M[0] + M[1]*M[2], n1 = M[0]*M[1] + M[1]*M[3];
        double n2 = M[2]*M[0] + M[3]*M[2], n3 = M[2]*M[1] + M[3]*M[3];
        M[0]=n0; M[1]=n1; M[2]=n2; M[3]=n3;
    }
    for (int k = 0; k < 6; ++k) {            // A64^(2^k)
        S->m[k][0] = (float)M[0]; S->m[k][1] = (float)M[1];
        S->m[k][2] = (float)M[2]; S->m[k][3] = (float)M[3];
        double n0 = M[0]*M[0] + M[1]*M[2], n1 = M[0]*M[1] + M[1]*M[3];
        double n2 = M[2]*M[0] + M[3]*M[2], n3 = M[2]*M[1] + M[3]*M[3];
        M[0]=n0; M[1]=n1; M[2]=n2; M[3]=n3;
    }
}

extern "C" void kernel_launch(void* const* d_in, const int* in_sizes, int n_in,
                              void* d_out, int out_size, void* d_ws, size_t ws_size,
                              hipStream_t stream) {
    const float* x = (const float*)d_in[0];
    float* out = (float*)d_out;

    const int T = 441000;
    int total = in_sizes[0];
    int B = total / T;                                  // 32

    BQ f1, f2, f3; double a1, a2;
    ScanM s1, s2, s3;
    make_eq(1000.0, 6.0, 1.0, &f1, &a1, &a2);           fill_scan(a1, a2, &s1);
    make_lp(8000.0, 0.7071067811865476, &f2, &a1, &a2); fill_scan(a1, a2, &s2);
    make_hp(300.0, 0.7071067811865476, &f3, &a1, &a2);  fill_scan(a1, a2, &s3);

    int blocksPerRow = (T + OUTSPAN - 1) / OUTSPAN;     // 113
    dim3 grid(blocksPerRow, B);
    hipLaunchKernelGGL(biquad3_kernel, grid, dim3(64), 0, stream,
                       x, out, T, f1, f2, f3, s1, s2, s3);
}

// Round 9
// 107.232 us; speedup vs baseline: 1.1912x; 1.1810x over previous
//
#include <hip/hip_runtime.h>
#include <math.h>

// RandomMicEQ: cascade of 3 biquads (EQ -> LP -> HP), stage outputs clamped
// to [-1,1], recursion history UNCLAMPED (matches jax ref).
//
// R12: fit the 64-VGPR budget instead of fighting the allocator.
// Evidence chain R8/R10/R11: for 64-thread blocks the AMDGPU backend
// targets 8 waves/SIMD (64-VGPR budget) and wholesale-demotes d[64] to
// scratch (VGPR_Count=64 four rounds running; scratch visible as WRITE
// 55->79MB leaking past L2). (64,2) avoided the spill but halved residency.
// Fix: L_CHUNK 64->32. d[32]+~25 overhead ~= 58 <= 64 -> no spill AND
// 8 waves/SIMD. W=192 kept via NWARM=6 (at W=96 the HP@300Hz transient
// ~1.6e-2 would breach the 7.7e-3 threshold). Work = 238 blocks/row x 32
// rows = 7.4 waves/SIMD, fully co-resident in ONE round.
// Diagnostic: WRITE_SIZE ~55MB = spill gone; 79MB = still spilling.
//
// Algorithm (R6-R9): per stage, lanes run a zero-state local pass in
// registers; 6-step Kogge-Stone scan of 2-dim states (A^32 powers now,
// host double) reconstructs exact init states; correction = homogeneous
// recursion seeded by init state; clamp at consumption; stage-k correction
// fused into stage-(k+1) local sweep (4 sweeps total). Block boundary =
// zero state 192 samples early (6 warm chunks discarded). Block 0 exact.
// Input: direct strided global->register (disjoint chunks, 1.10x fetch).
// Output: LDS pitch-33 staging + full-line coalesced stores (R2: scattered
// stores cause RMW write amplification).

struct BQ { float b0, b1, b2, a1, a2; };
struct ScanM { float m[6][4]; };       // A32^(2^k), k=0..5, row-major 2x2

#define L_CHUNK 32
#define NWARM   6
#define NCH     64                     // chunks per block (= lanes)
#define NOUT    (NCH - NWARM)          // 58
#define SPAN    (NCH * L_CHUNK)        // 2048
#define OUTSPAN (NOUT * L_CHUNK)       // 1856
#define WOFF    (NWARM * L_CHUNK)      // 192
#define PITCH   33                     // LDS pitch: (lane+t)%32 banks, 2-way
#define BUF_P   (NCH * PITCH)          // 2112 dwords = 8448 B

__device__ __forceinline__ float clamp1(float v) {
    return fminf(fmaxf(v, -1.f), 1.f);
}

// Kogge-Stone inclusive scan of s_i = A32 * s_{i-1} + loc_i over 64 lanes
#define KS_SCAN(S)                                                   \
    _Pragma("unroll")                                                \
    for (int k = 0; k < 6; ++k) {                                    \
        float px = __shfl_up(sx, 1 << k, 64);                        \
        float py = __shfl_up(sy, 1 << k, 64);                        \
        if (lane >= (1 << k)) {                                      \
            sx += S.m[k][0]*px + S.m[k][1]*py;                       \
            sy += S.m[k][2]*px + S.m[k][3]*py;                       \
        }                                                            \
    }

__global__ __launch_bounds__(64) void biquad3_kernel(
    const float* __restrict__ x, float* __restrict__ out, int T,
    BQ F1, BQ F2, BQ F3, ScanM S1, ScanM S2, ScanM S3)
{
    __shared__ float buf[BUF_P];             // output staging only

    const int lane = threadIdx.x;
    const int row  = blockIdx.y;
    const int col0 = blockIdx.x * OUTSPAN;
    const int base = col0 - WOFF;            // may be < 0 (zero-padded)

    const float* xr = x   + (size_t)row * T;
    float*       yr = out + (size_t)row * T;

    float d[L_CHUNK];                        // 32 VGPRs: must stay registers

    // ---- direct strided load of lane's 32-sample chunk ----
    const int cbase = base + lane * L_CHUNK;
    if (cbase >= 0 && cbase + L_CHUNK <= T) {
#pragma unroll
        for (int j = 0; j < 8; ++j) {
            float4 v = *(const float4*)(xr + cbase + 4*j);
            d[4*j+0] = v.x; d[4*j+1] = v.y; d[4*j+2] = v.z; d[4*j+3] = v.w;
        }
    } else {                                 // boundary lanes only
#pragma unroll
        for (int j = 0; j < L_CHUNK; ++j) {
            int g = cbase + j;
            d[j] = ((unsigned)g < (unsigned)T) ? xr[g] : 0.f;
        }
    }

    // ================= pass 1: stage-1 local filter =================
    float ph1 = __shfl_up(d[31], 1, 64);     // raw-input prehistory
    float ph2 = __shfl_up(d[30], 1, 64);
    if (lane == 0) { ph1 = 0.f; ph2 = 0.f; }
    float xx1 = ph1, xx2 = ph2, yy1 = 0.f, yy2 = 0.f;
#pragma unroll
    for (int t = 0; t < L_CHUNK; ++t) {
        float v = d[t];
        float f = F1.b0*v + F1.b1*xx1 + F1.b2*xx2;
        float y = (f - F1.a2*yy2) - F1.a1*yy1;
        xx2 = xx1; xx1 = v; yy2 = yy1; yy1 = y;
        d[t] = y;                            // unclamped stage-1 local
    }
    float sx = yy1, sy = yy2;
    KS_SCAN(S1)
    float ix = __shfl_up(sx, 1, 64);         // exclusive: my init (y-1,y-2)
    float iy = __shfl_up(sy, 1, 64);
    if (lane == 0) { ix = 0.f; iy = 0.f; }
    // corrected stage-1 tail (closed form: A^32 row0 / row1) -> prehistory
    float ct1 = clamp1(d[31] + S1.m[0][0]*ix + S1.m[0][1]*iy);
    float ct2 = clamp1(d[30] + S1.m[0][2]*ix + S1.m[0][3]*iy);
    ph1 = __shfl_up(ct1, 1, 64);
    ph2 = __shfl_up(ct2, 1, 64);
    if (lane == 0) { ph1 = 0.f; ph2 = 0.f; }

    // ===== pass 2 fused: stage-1 correction+clamp + stage-2 local =====
    float h1 = ix, h2 = iy;
    xx1 = ph1; xx2 = ph2; yy1 = 0.f; yy2 = 0.f;
#pragma unroll
    for (int t = 0; t < L_CHUNK; ++t) {
        float h = -F1.a1*h1 - F1.a2*h2;      // stage-1 homogeneous corr
        float v = clamp1(d[t] + h);          // exact stage-1 output
        h2 = h1; h1 = h;
        float f = F2.b0*v + F2.b1*xx1 + F2.b2*xx2;
        float y = (f - F2.a2*yy2) - F2.a1*yy1;
        xx2 = xx1; xx1 = v; yy2 = yy1; yy1 = y;
        d[t] = y;                            // unclamped stage-2 local
    }
    sx = yy1; sy = yy2;
    KS_SCAN(S2)
    ix = __shfl_up(sx, 1, 64);
    iy = __shfl_up(sy, 1, 64);
    if (lane == 0) { ix = 0.f; iy = 0.f; }
    ct1 = clamp1(d[31] + S2.m[0][0]*ix + S2.m[0][1]*iy);
    ct2 = clamp1(d[30] + S2.m[0][2]*ix + S2.m[0][3]*iy);
    ph1 = __shfl_up(ct1, 1, 64);
    ph2 = __shfl_up(ct2, 1, 64);
    if (lane == 0) { ph1 = 0.f; ph2 = 0.f; }

    // ===== pass 3 fused: stage-2 correction+clamp + stage-3 local =====
    h1 = ix; h2 = iy;
    xx1 = ph1; xx2 = ph2; yy1 = 0.f; yy2 = 0.f;
#pragma unroll
    for (int t = 0; t < L_CHUNK; ++t) {
        float h = -F2.a1*h1 - F2.a2*h2;
        float v = clamp1(d[t] + h);
        h2 = h1; h1 = h;
        float f = F3.b0*v + F3.b1*xx1 + F3.b2*xx2;
        float y = (f - F3.a2*yy2) - F3.a1*yy1;
        xx2 = xx1; xx1 = v; yy2 = yy1; yy1 = y;
        d[t] = y;                            // unclamped stage-3 local
    }
    sx = yy1; sy = yy2;
    KS_SCAN(S3)
    ix = __shfl_up(sx, 1, 64);
    iy = __shfl_up(sy, 1, 64);
    if (lane == 0) { ix = 0.f; iy = 0.f; }

    // ===== stage-3 correction + clamp, write to LDS staging =====
    h1 = ix; h2 = iy;
    {
        float* myrow = buf + lane * PITCH;   // banks (lane+t)%32: 2-way free
#pragma unroll
        for (int t = 0; t < L_CHUNK; ++t) {
            float h = -F3.a1*h1 - F3.a2*h2;
            myrow[t] = clamp1(d[t] + h);
            h2 = h1; h1 = h;
        }
    }
    __syncthreads();

    // ---- coalesced flush of the 58 output chunks ----
    for (int mm = lane * 4; mm < OUTSPAN; mm += 256) {
        int m = WOFF + mm;
        int c = m >> 5;                      // chunk index
        int j = m & (L_CHUNK - 1);           // j%4==0
        int g = col0 + mm;
        if (g < T) {                         // g%4==0, T%4==0 -> g+4<=T
            const float* s = buf + c * PITCH + j;
            float4 v4 = make_float4(s[0], s[1], s[2], s[3]);
            *(float4*)(yr + g) = v4;
        }
    }
}

// ---- host side ----------------------------------------------------------

static void norm_ba(double b0, double b1, double b2,
                    double a0, double a1, double a2, BQ* r,
                    double* oa1, double* oa2) {
    r->b0 = (float)(b0/a0); r->b1 = (float)(b1/a0); r->b2 = (float)(b2/a0);
    r->a1 = (float)(a1/a0); r->a2 = (float)(a2/a0);
    // scan matrices built from the float-rounded coeffs the kernel iterates
    *oa1 = (double)r->a1; *oa2 = (double)r->a2;
}

static void make_eq(double f0, double gain_db, double Q, BQ* r, double* a1, double* a2) {
    const double SR = 44100.0;
    double w0 = 2.0 * M_PI * f0 / SR;
    double alpha = sin(w0) / (2.0 * Q);
    double A = pow(10.0, gain_db / 40.0);
    norm_ba(1.0 + alpha*A, -2.0*cos(w0), 1.0 - alpha*A,
            1.0 + alpha/A, -2.0*cos(w0), 1.0 - alpha/A, r, a1, a2);
}

static void make_lp(double cutoff, double Q, BQ* r, double* a1, double* a2) {
    const double SR = 44100.0;
    double w0 = 2.0 * M_PI * cutoff / SR;
    double alpha = sin(w0) / (2.0 * Q);
    double c = cos(w0);
    norm_ba((1.0-c)/2.0, 1.0-c, (1.0-c)/2.0,
            1.0+alpha, -2.0*c, 1.0-alpha, r, a1, a2);
}

static void make_hp(double cutoff, double Q, BQ* r, double* a1, double* a2) {
    const double SR = 44100.0;
    double w0 = 2.0 * M_PI * cutoff / SR;
    double alpha = sin(w0) / (2.0 * Q);
    double c = cos(w0);
    norm_ba((1.0+c)/2.0, -(1.0+c), (1.0+c)/2.0,
            1.0+alpha, -2.0*c, 1.0-alpha, r, a1, a2);
}

// S.m[k] = A32^(2^k) where A = [[-a1,-a2],[1,0]], all double math
static void fill_scan(double a1, double a2, ScanM* S) {
    double M[4] = { -a1, -a2, 1.0, 0.0 };    // A^1
    for (int i = 0; i < 5; ++i) {            // -> A^32
        double n0 = M[0]*M[0] + M[1]*M[2], n1 = M[0]*M[1] + M[1]*M[3];
        double n2 = M[2]*M[0] + M[3]*M[2], n3 = M[2]*M[1] + M[3]*M[3];
        M[0]=n0; M[1]=n1; M[2]=n2; M[3]=n3;
    }
    for (int k = 0; k < 6; ++k) {            // A32^(2^k)
        S->m[k][0] = (float)M[0]; S->m[k][1] = (float)M[1];
        S->m[k][2] = (float)M[2]; S->m[k][3] = (float)M[3];
        double n0 = M[0]*M[0] + M[1]*M[2], n1 = M[0]*M[1] + M[1]*M[3];
        double n2 = M[2]*M[0] + M[3]*M[2], n3 = M[2]*M[1] + M[3]*M[3];
        M[0]=n0; M[1]=n1; M[2]=n2; M[3]=n3;
    }
}

extern "C" void kernel_launch(void* const* d_in, const int* in_sizes, int n_in,
                              void* d_out, int out_size, void* d_ws, size_t ws_size,
                              hipStream_t stream) {
    const float* x = (const float*)d_in[0];
    float* out = (float*)d_out;

    const int T = 441000;
    int total = in_sizes[0];
    int B = total / T;                                  // 32

    BQ f1, f2, f3; double a1, a2;
    ScanM s1, s2, s3;
    make_eq(1000.0, 6.0, 1.0, &f1, &a1, &a2);           fill_scan(a1, a2, &s1);
    make_lp(8000.0, 0.7071067811865476, &f2, &a1, &a2); fill_scan(a1, a2, &s2);
    make_hp(300.0, 0.7071067811865476, &f3, &a1, &a2);  fill_scan(a1, a2, &s3);

    int blocksPerRow = (T + OUTSPAN - 1) / OUTSPAN;     // 238
    dim3 grid(blocksPerRow, B);
    hipLaunchKernelGGL(biquad3_kernel, grid, dim3(64), 0, stream,
                       x, out, T, f1, f2, f3, s1, s2, s3);
}